// Round 4
// baseline (353.007 us; speedup 1.0000x reference)
//
#include <hip/hip_runtime.h>

typedef __attribute__((ext_vector_type(8))) __bf16 bf16x8;
typedef __attribute__((ext_vector_type(8))) unsigned short u16x8;
typedef __attribute__((ext_vector_type(4))) float f32x4;

// Static device scratch (bf16 intermediates): q [2048][2048], k [2048][512],
// v [2048][512], att [2048][2048]. No d_ws dependency.
#define QOFF 0
#define KOFF (2048 * 2048)
#define VOFF (KOFF + 2048 * 512)
#define AOFF (VOFF + 2048 * 512)
__device__ ushort g_scratch[AOFF + 2048 * 2048];

// nested (matryoshka) index -> full-layout index, H heads/groups, 128 per head
// sizes [32,64,128]: per-head segments of 32/32/64
__device__ __forceinline__ int nest_map(int n, int H) {
    int h = n >> 7, j = n & 127;
    if (j < 32) return h * 32 + j;
    if (j < 64) return H * 32 + h * 32 + (j - 32);
    return H * 64 + h * 64 + (j - 64);
}

__device__ __forceinline__ ushort f2bf(float f) {
    unsigned u = __builtin_bit_cast(unsigned, f);
    u += 0x7fffu + ((u >> 16) & 1u);
    return (ushort)(u >> 16);
}
__device__ __forceinline__ bf16x8 ld_frag(const ushort* p) {
    return __builtin_bit_cast(bf16x8, *(const u16x8*)p);
}

// ---------------------------------------------------------------------------
// Fused GEMM. Inputs (x / W / bias) are FP32 per the reference; they are
// rounded to bf16 during LDS staging. fp32 accumulate.
// B staged transposed on the fly from natural [K][N] weights; matryoshka
// reorder folded into column (mode 0) or row (mode 1) index of W.
// 64x64 tile, BK=64, 4 waves (2x2), 32x32 per wave.
// mode 0: A = x (fp32), outputs -> g_scratch q|k|v (bf16).
// mode 1: A = g_scratch att (bf16), output -> oext (fp32 d_out).
// ---------------------------------------------------------------------------
__global__ __launch_bounds__(256) void gemm_fused_kernel(
    const float* __restrict__ Af,
    const float* __restrict__ W0, const float* __restrict__ W1,
    const float* __restrict__ W2,
    const float* __restrict__ b0, const float* __restrict__ b1,
    const float* __restrict__ b2,
    float* __restrict__ oext, int mode)
{
    __shared__ ushort As[64][72];   // A (bf16), 144B rows, 16B-aligned
    __shared__ ushort Bs[64][72];   // B^T (bf16), XOR-octet swizzled columns
    const int n0 = blockIdx.x * 64;
    const int m0 = blockIdx.y * 64;
    const int tid = threadIdx.x;
    const int lane = tid & 63, wid = tid >> 6;
    const int wm = wid & 1, wn = wid >> 1;
    const int quad = lane >> 4, l16 = lane & 15;
    const int srow = tid >> 3, soct = tid & 7;

    // block-uniform routing
    const float* W; const float* bias;
    const ushort* Abf = nullptr;
    ushort* outS = nullptr;
    int rowlen, H, c0, oldim, bmaprow;
    if (mode == 1) {
        Abf = g_scratch + AOFF; W = W0; bias = b0;
        rowlen = 2048; H = 16; c0 = n0; oldim = 2048; bmaprow = 1;
    } else {
        bmaprow = 0;
        if (n0 < 2048)      { W = W0; bias = b0; outS = g_scratch + QOFF; rowlen = 2048; H = 16; c0 = n0;        oldim = 2048; }
        else if (n0 < 2560) { W = W1; bias = b1; outS = g_scratch + KOFF; rowlen = 512;  H = 4;  c0 = n0 - 2048; oldim = 512;  }
        else                { W = W2; bias = b2; outS = g_scratch + VOFF; rowlen = 512;  H = 4;  c0 = n0 - 2560; oldim = 512;  }
    }

    f32x4 acc00{}, acc01{}, acc10{}, acc11{};

    for (int kt = 0; kt < 32; ++kt) {
        const int k0 = kt * 64;
        #pragma unroll
        for (int rep = 0; rep < 2; ++rep) {
            int krow = srow + rep * 32;
            // --- stage A ---
            if (mode == 0) {
                float4 f0 = *(const float4*)&Af[(size_t)(m0 + krow) * 2048 + k0 + soct * 8];
                float4 f1 = *(const float4*)&Af[(size_t)(m0 + krow) * 2048 + k0 + soct * 8 + 4];
                union { uint4 v; ushort u[8]; } a;
                a.u[0] = f2bf(f0.x); a.u[1] = f2bf(f0.y); a.u[2] = f2bf(f0.z); a.u[3] = f2bf(f0.w);
                a.u[4] = f2bf(f1.x); a.u[5] = f2bf(f1.y); a.u[6] = f2bf(f1.z); a.u[7] = f2bf(f1.w);
                *(uint4*)&As[krow][soct * 8] = a.v;
            } else {
                *(uint4*)&As[krow][soct * 8] =
                    *(const uint4*)&Abf[(size_t)(m0 + krow) * 2048 + k0 + soct * 8];
            }
            // --- stage B^T from natural fp32 W ---
            int wrow = bmaprow ? nest_map(k0 + krow, 16) : (k0 + krow);
            int wcol = bmaprow ? (c0 + soct * 8) : nest_map(c0 + soct * 8, H);
            float4 w0 = *(const float4*)&W[(size_t)wrow * rowlen + wcol];
            float4 w1 = *(const float4*)&W[(size_t)wrow * rowlen + wcol + 4];
            float wv[8] = {w0.x, w0.y, w0.z, w0.w, w1.x, w1.y, w1.z, w1.w};
            #pragma unroll
            for (int j = 0; j < 8; ++j) {
                int r = soct * 8 + j;                      // B row (n in tile)
                Bs[r][krow ^ (soct << 3)] = f2bf(wv[j]);   // swizzle keyed on r>>3
            }
        }
        __syncthreads();
        #pragma unroll
        for (int kc = 0; kc < 2; ++kc) {
            const int br0 = wn * 32 + l16, br1 = br0 + 16;
            const int sw0 = ((br0 >> 3) & 7) << 3, sw1 = ((br1 >> 3) & 7) << 3;
            bf16x8 a0 = ld_frag(&As[wm * 32 + l16][kc * 32 + quad * 8]);
            bf16x8 a1 = ld_frag(&As[wm * 32 + 16 + l16][kc * 32 + quad * 8]);
            bf16x8 bb0 = ld_frag(&Bs[br0][(kc * 32 + quad * 8) ^ sw0]);
            bf16x8 bb1 = ld_frag(&Bs[br1][(kc * 32 + quad * 8) ^ sw1]);
            acc00 = __builtin_amdgcn_mfma_f32_16x16x32_bf16(a0, bb0, acc00, 0, 0, 0);
            acc01 = __builtin_amdgcn_mfma_f32_16x16x32_bf16(a0, bb1, acc01, 0, 0, 0);
            acc10 = __builtin_amdgcn_mfma_f32_16x16x32_bf16(a1, bb0, acc10, 0, 0, 0);
            acc11 = __builtin_amdgcn_mfma_f32_16x16x32_bf16(a1, bb1, acc11, 0, 0, 0);
        }
        __syncthreads();
    }

    f32x4 accs[2][2] = {{acc00, acc01}, {acc10, acc11}};
    #pragma unroll
    for (int sm = 0; sm < 2; ++sm)
    #pragma unroll
    for (int sn = 0; sn < 2; ++sn)
    #pragma unroll
    for (int i = 0; i < 4; ++i) {
        int row = m0 + wm * 32 + sm * 16 + quad * 4 + i;
        int loc = wn * 32 + sn * 16 + l16;             // tile-local col
        float v = accs[sm][sn][i]
                + bias[bmaprow ? (c0 + loc) : nest_map(c0 + loc, H)];
        if (mode == 0) outS[(size_t)row * oldim + c0 + loc] = f2bf(v);
        else           oext[(size_t)row * 2048 + c0 + loc] = v;
    }
}

// ---------------------------------------------------------------------------
// Matryoshka flash attention (bf16 scratch in/out). Grid (S/64, 16, 2),
// 4 waves, wave w owns q-rows [w*16, w*16+16). Levels 0:32/32:64/64:128
// with cumulative dp, scales 1/sqrt(32|64|128).
// ---------------------------------------------------------------------------
__global__ __launch_bounds__(256) void attn_kernel()
{
    const ushort* qb = g_scratch + QOFF;   // [B,S,16,128] nested
    const ushort* kb = g_scratch + KOFF;   // [B,S,4,128]
    const ushort* vb = g_scratch + VOFF;   // [B,S,4,128]
    ushort* att = g_scratch + AOFF;        // [B,S,16,128] nested

    __shared__ ushort Qs[64][136];
    __shared__ ushort Ks[64][136];
    __shared__ ushort Vt[128][72];   // V transposed, XOR-octet swizzled
    __shared__ ushort Ps[64][72];    // P round-trip (C-layout -> A-layout)

    const int qt = blockIdx.x, h = blockIdx.y, b = blockIdx.z;
    const int g = h >> 2;
    const int q0 = qt * 64;
    const int tid = threadIdx.x;
    const int lane = tid & 63, w = tid >> 6;
    const int quad = lane >> 4, l16 = lane & 15;

    {   // Q tile: 64 rows x 128
        int r = tid >> 4, oct = tid & 15;
        #pragma unroll
        for (int rep = 0; rep < 4; ++rep) {
            int row = r + rep * 16;
            *(uint4*)&Qs[row][oct * 8] =
                *(const uint4*)&qb[(size_t)((b * 1024 + q0 + row) * 16 + h) * 128 + oct * 8];
        }
    }

    float m_s[3][4], l_s[3][4];
    #pragma unroll
    for (int l = 0; l < 3; ++l)
        #pragma unroll
        for (int i = 0; i < 4; ++i) { m_s[l][i] = -1e9f; l_s[l][i] = 0.0f; }
    f32x4 oacc[8];
    #pragma unroll
    for (int t2 = 0; t2 < 8; ++t2) oacc[t2] = f32x4{0.f, 0.f, 0.f, 0.f};

    f32x4 sdp[4];
    const f32x4 fz = {0.f, 0.f, 0.f, 0.f};

    auto attn_level = [&](int lvl, float scale, int obase, int ontiles, int voff,
                          bool diag, int k0) {
        float sv[4][4], mx[4];
        #pragma unroll
        for (int i = 0; i < 4; ++i) mx[i] = -1e9f;
        #pragma unroll
        for (int n = 0; n < 4; ++n)
            #pragma unroll
            for (int i = 0; i < 4; ++i) {
                float x = sdp[n][i] * scale;
                if (diag) {
                    int kc = k0 + n * 16 + l16;
                    int qr = q0 + w * 16 + quad * 4 + i;
                    if (kc > qr) x = -1e9f;
                }
                sv[n][i] = x;
                mx[i] = fmaxf(mx[i], x);
            }
        #pragma unroll
        for (int d = 1; d < 16; d <<= 1)
            #pragma unroll
            for (int i = 0; i < 4; ++i) mx[i] = fmaxf(mx[i], __shfl_xor(mx[i], d, 64));
        float al[4], rs[4];
        #pragma unroll
        for (int i = 0; i < 4; ++i) {
            float mn = fmaxf(m_s[lvl][i], mx[i]);
            al[i] = __expf(m_s[lvl][i] - mn);
            m_s[lvl][i] = mn;
            rs[i] = 0.f;
        }
        #pragma unroll
        for (int n = 0; n < 4; ++n)
            #pragma unroll
            for (int i = 0; i < 4; ++i) {
                float p = __expf(sv[n][i] - m_s[lvl][i]);
                sv[n][i] = p;
                rs[i] += p;
            }
        #pragma unroll
        for (int d = 1; d < 16; d <<= 1)
            #pragma unroll
            for (int i = 0; i < 4; ++i) rs[i] += __shfl_xor(rs[i], d, 64);
        #pragma unroll
        for (int i = 0; i < 4; ++i) l_s[lvl][i] = l_s[lvl][i] * al[i] + rs[i];
        for (int t = 0; t < ontiles; ++t)
            #pragma unroll
            for (int i = 0; i < 4; ++i) oacc[obase + t][i] *= al[i];
        // P: C-layout regs -> LDS, barrier-bracketed (WAR + RAW)
        __syncthreads();
        #pragma unroll
        for (int n = 0; n < 4; ++n)
            #pragma unroll
            for (int i = 0; i < 4; ++i)
                Ps[w * 16 + quad * 4 + i][n * 16 + l16] = f2bf(sv[n][i]);
        __syncthreads();
        // PV: A = P (A-layout), B = V (swizzled Vt)
        #pragma unroll
        for (int kc = 0; kc < 2; ++kc) {
            bf16x8 pa = ld_frag(&Ps[w * 16 + l16][kc * 32 + quad * 8]);
            for (int t = 0; t < ontiles; ++t) {
                int vd = voff + t * 16 + l16;
                bf16x8 vf = ld_frag(&Vt[vd][(kc * 32 + quad * 8) ^ (((vd >> 3) & 7) << 3)]);
                oacc[obase + t] =
                    __builtin_amdgcn_mfma_f32_16x16x32_bf16(pa, vf, oacc[obase + t], 0, 0, 0);
            }
        }
    };

    for (int kt = 0; kt <= qt; ++kt) {
        const int k0 = kt * 64;
        {   // stage K natural, V transposed+swizzled
            int r = tid >> 4, oct = tid & 15;
            #pragma unroll
            for (int rep = 0; rep < 4; ++rep) {
                int row = r + rep * 16;
                size_t base = (size_t)((b * 1024 + k0 + row) * 4 + g) * 128 + oct * 8;
                *(uint4*)&Ks[row][oct * 8] = *(const uint4*)&kb[base];
                union { uint4 v; ushort u[8]; } cv;
                cv.v = *(const uint4*)&vb[base];
                #pragma unroll
                for (int i = 0; i < 8; ++i) {
                    int d = oct * 8 + i;
                    Vt[d][row ^ (((d >> 3) & 7) << 3)] = cv.u[i];
                }
            }
        }
        __syncthreads();

        bf16x8 qa[4];
        #pragma unroll
        for (int kc = 0; kc < 4; ++kc)
            qa[kc] = ld_frag(&Qs[w * 16 + l16][kc * 32 + quad * 8]);

        const bool diag = (kt == qt);
        #pragma unroll
        for (int n = 0; n < 4; ++n)
            sdp[n] = __builtin_amdgcn_mfma_f32_16x16x32_bf16(
                qa[0], ld_frag(&Ks[n * 16 + l16][quad * 8]), fz, 0, 0, 0);
        attn_level(0, 0.1767766953f, 0, 2, 0, diag, k0);
        #pragma unroll
        for (int n = 0; n < 4; ++n)
            sdp[n] = __builtin_amdgcn_mfma_f32_16x16x32_bf16(
                qa[1], ld_frag(&Ks[n * 16 + l16][32 + quad * 8]), sdp[n], 0, 0, 0);
        attn_level(1, 0.125f, 2, 2, 32, diag, k0);
        #pragma unroll
        for (int kc = 2; kc < 4; ++kc)
            #pragma unroll
            for (int n = 0; n < 4; ++n)
                sdp[n] = __builtin_amdgcn_mfma_f32_16x16x32_bf16(
                    qa[kc], ld_frag(&Ks[n * 16 + l16][kc * 32 + quad * 8]), sdp[n], 0, 0, 0);
        attn_level(2, 0.0883883476f, 4, 4, 64, diag, k0);

        __syncthreads();
    }

    float inv[3][4];
    #pragma unroll
    for (int l = 0; l < 3; ++l)
        #pragma unroll
        for (int i = 0; i < 4; ++i) {
            float L = l_s[l][i];
            inv[l][i] = (L > 0.f) ? (1.0f / L) : 0.f;
        }
    #pragma unroll
    for (int t = 0; t < 8; ++t) {
        int lvl = (t < 2) ? 0 : (t < 4) ? 1 : 2;
        #pragma unroll
        for (int i = 0; i < 4; ++i) {
            int srow = q0 + w * 16 + quad * 4 + i;
            att[(size_t)((b * 1024 + srow) * 16 + h) * 128 + t * 16 + l16] =
                f2bf(oacc[t][i] * inv[lvl][i]);
        }
    }
}

// ---------------------------------------------------------------------------
extern "C" void kernel_launch(void* const* d_in, const int* in_sizes, int n_in,
                              void* d_out, int out_size, void* d_ws, size_t ws_size,
                              hipStream_t stream)
{
    // Reference setup_inputs(): ALL tensors are jnp.float32 -> const float*.
    const float* x  = (const float*)d_in[0];
    // d_in[1] = mask (bool tril): applied analytically — unused
    const float* Wq = (const float*)d_in[2];
    const float* bq = (const float*)d_in[3];
    const float* Wk = (const float*)d_in[4];
    const float* bk = (const float*)d_in[5];
    const float* Wv = (const float*)d_in[6];
    const float* bv = (const float*)d_in[7];
    const float* Wo = (const float*)d_in[8];
    const float* bo = (const float*)d_in[9];
    float* out = (float*)d_out;            // reference output dtype: float32
    (void)d_ws; (void)ws_size;             // intermediates live in g_scratch

    dim3 blk(256, 1, 1);
    hipLaunchKernelGGL(gemm_fused_kernel, dim3(48, 32), blk, 0, stream,
                       x, Wq, Wk, Wv, bq, bk, bv, (float*)nullptr, 0);
    hipLaunchKernelGGL(attn_kernel, dim3(16, 16, 2), blk, 0, stream);
    hipLaunchKernelGGL(gemm_fused_kernel, dim3(32, 32), blk, 0, stream,
                       (const float*)nullptr, Wo, nullptr, nullptr,
                       bo, nullptr, nullptr, out, 1);
}